// Round 8
// baseline (186.157 us; speedup 1.0000x reference)
//
#include <hip/hip_runtime.h>

#define D 128
#define CAP 48      // col slots per node; P(Poisson(8) >= 48) ~ 1e-41
#define SCAP 160    // records per shard; P(Poisson(64) >= 160) ~ 1e-24

typedef __attribute__((ext_vector_type(8))) short bf16x8;
typedef __attribute__((ext_vector_type(4))) float f32x4;
typedef __attribute__((ext_vector_type(8))) unsigned short u16x8;

// ---------- bf16 helpers (manual, RNE) ----------
__device__ inline unsigned short f2bf(float f) {
    unsigned u = __float_as_uint(f);
    unsigned r = (u + 0x7fff + ((u >> 16) & 1)) >> 16;
    return (unsigned short)r;
}
__device__ inline float bf2f(unsigned short s) {
    return __uint_as_float((unsigned)s << 16);
}

// ---------- graph build, pass 1: bucket edges by dst>>6, sharded by XCD ----
// Record = (src<<6)|(dst&63), 4B. Shard = (dst>>6)*8 + (blockIdx&7): each
// append stream is written by ~one XCD -> tail lines stay in that L2 ->
// full write merging (round 7: unsharded scatter had 47.5 MB line-granule
// writes for 3.2 MB of payload). XCD mapping is a perf heuristic only.

__device__ inline void bput(int s, int d, int xcd, int* __restrict__ bcnt,
                            unsigned* __restrict__ brec) {
    int sh = ((d >> 6) << 3) + xcd;
    int p = atomicAdd(&bcnt[sh], 1);
    if (p < SCAP) brec[(size_t)sh * SCAP + p] = ((unsigned)s << 6) | (unsigned)(d & 63);
}

__global__ void k_bucket(const int* __restrict__ ei, int* __restrict__ bcnt,
                         unsigned* __restrict__ brec, int E) {
    int xcd = blockIdx.x & 7;
    int e0 = (blockIdx.x * 256 + threadIdx.x) * 4;
    if (e0 + 3 < E) {
        int4 s4 = *(const int4*)&ei[e0];
        int4 d4 = *(const int4*)&ei[E + e0];
        bput(s4.x, d4.x, xcd, bcnt, brec);
        bput(s4.y, d4.y, xcd, bcnt, brec);
        bput(s4.z, d4.z, xcd, bcnt, brec);
        bput(s4.w, d4.w, xcd, bcnt, brec);
    } else {
        for (int e = e0; e < E; e++) bput(ei[e], ei[E + e], xcd, bcnt, brec);
    }
}

// ---------- graph build, pass 2: one block per bucket -> col + degree ------
// Reads the bucket's 8 shards (~512 records) sequentially, LDS-atomic
// cursors for its 64 nodes, scatters src into the bucket's 12KB col region
// (temporally clustered -> L2-merged), writes degrees coalesced.

__global__ __launch_bounds__(256) void k_build(const int* __restrict__ bcnt,
                                               const unsigned* __restrict__ brec,
                                               int* __restrict__ cnt,
                                               int* __restrict__ col, int N) {
    __shared__ int c64[64];
    __shared__ int sofs[9];
    int b = blockIdx.x, t = threadIdx.x;
    if (t < 64) c64[t] = 0;
    if (t == 0) {
        int run = 0;
        for (int s = 0; s < 8; s++) {
            sofs[s] = run;
            int c = bcnt[b * 8 + s];
            run += (c < SCAP) ? c : SCAP;
        }
        sofs[8] = run;
    }
    __syncthreads();
    int total = sofs[8];
    for (int idx = t; idx < total; idx += 256) {
        int s = 0;
        while (idx >= sofs[s + 1]) s++;          // <=8 iters
        unsigned rec = brec[(size_t)(b * 8 + s) * SCAP + (idx - sofs[s])];
        int dl = rec & 63;
        int p = atomicAdd(&c64[dl], 1);
        if (p < CAP) col[(size_t)(b * 64 + dl) * CAP + p] = (int)(rec >> 6);
    }
    __syncthreads();
    if (t < 64) {
        int node = b * 64 + t;
        if (node < N) cnt[node] = (c64[t] < CAP) ? c64[t] : CAP;
    }
}

// ---------- dense: g = bf16( (in @ W^T) * rsqrt(deg+1) ) via MFMA ----------
// C = W · x^T with mfma_f32_16x16x32_bf16: A-frag = W[j][k..], B-frag = x[r][k..],
// both contiguous-k row reads. C layout (m89): col(lane&15)=node, row=(lane>>4)*4+reg.
// W staged bf16 in LDS once per block (pad to LROW -> conflict-free);
// x staged per-wave (wave-private rows -> no barriers in main loop).
// #pragma unroll 1 on ks-loop: round-3 lesson (full unroll -> mass hoist/spill).

#define LROW 136   // padded row stride in ushorts (272 B)

template <bool IN_BF16>
__global__ __launch_bounds__(256, 2) void k_gemm_mfma(
        const void* __restrict__ in_v, const float* __restrict__ W,
        const int* __restrict__ cnt, unsigned short* __restrict__ g,
        int N, int ntiles) {
    __shared__ __align__(16) unsigned short wl[D * LROW];   // 34.8 KB
    __shared__ __align__(16) unsigned short xl[D * LROW];   // 34.8 KB (128 nodes)
    int t = threadIdx.x;
    int w = t >> 6;          // wave 0..3
    int l = t & 63;
    int r16 = l & 15, g4 = l >> 4;

    {   // stage W fp32 -> bf16 LDS, once per block
        const float4* src = (const float4*)W;
#pragma unroll 4
        for (int i = 0; i < 16; i++) {
            int idx = i * 256 + t;              // 4096 float4
            int row = idx >> 5, c4 = idx & 31;
            float4 v = src[idx];
            ushort4 o = { f2bf(v.x), f2bf(v.y), f2bf(v.z), f2bf(v.w) };
            *(ushort4*)&wl[row * LROW + c4 * 4] = o;
        }
    }
    __syncthreads();

    for (int tile = blockIdx.x; tile < ntiles; tile += gridDim.x) {
        int node0 = tile * 128;
        int base = node0 + w * 32;              // this wave's 32 nodes

        if (!IN_BF16) {
            const float4* src = (const float4*)in_v;
#pragma unroll 4
            for (int i = 0; i < 16; i++) {
                int idx = i * 64 + l;           // 1024 float4 over 32 rows
                int rr = idx >> 5, c4 = idx & 31;
                int row = base + rr;
                float4 v = (row < N) ? src[(size_t)row * 32 + c4]
                                     : make_float4(0.f, 0.f, 0.f, 0.f);
                ushort4 o = { f2bf(v.x), f2bf(v.y), f2bf(v.z), f2bf(v.w) };
                *(ushort4*)&xl[(w * 32 + rr) * LROW + c4 * 4] = o;
            }
        } else {
            const u16x8* src = (const u16x8*)in_v;
#pragma unroll 4
            for (int i = 0; i < 8; i++) {
                int idx = i * 64 + l;           // 512 u16x8 over 32 rows
                int rr = idx >> 4, c8 = idx & 15;
                int row = base + rr;
                u16x8 v = {};
                if (row < N) v = src[(size_t)row * 16 + c8];
                *(u16x8*)&xl[(w * 32 + rr) * LROW + c8 * 8] = v;
            }
        }
        // no __syncthreads: rows are wave-private; compiler orders ds ops

        f32x4 acc0[8] = {};   // [jt] for nodes r16      (j = jt*16+g4*4+reg)
        f32x4 acc1[8] = {};   // [jt] for nodes 16+r16
        int xb0 = (w * 32 + r16) * LROW + g4 * 8;
        int xb1 = xb0 + 16 * LROW;
        int wb  = r16 * LROW + g4 * 8;
#pragma unroll 1
        for (int ks = 0; ks < 4; ks++) {
            bf16x8 b0 = *(const bf16x8*)&xl[xb0 + ks * 32];
            bf16x8 b1 = *(const bf16x8*)&xl[xb1 + ks * 32];
#pragma unroll
            for (int jt = 0; jt < 8; jt++) {
                bf16x8 a = *(const bf16x8*)&wl[wb + jt * 16 * LROW + ks * 32];
                acc0[jt] = __builtin_amdgcn_mfma_f32_16x16x32_bf16(a, b0, acc0[jt], 0, 0, 0);
                acc1[jt] = __builtin_amdgcn_mfma_f32_16x16x32_bf16(a, b1, acc1[jt], 0, 0, 0);
            }
        }

#pragma unroll
        for (int tt = 0; tt < 2; tt++) {
            int row = base + tt * 16 + r16;
            if (row < N) {
                float dv = rsqrtf((float)(cnt[row] + 1));   // dis[row]
#pragma unroll
                for (int jt = 0; jt < 8; jt++) {
                    f32x4 a = tt ? acc1[jt] : acc0[jt];
                    ushort4 o = { f2bf(a[0] * dv), f2bf(a[1] * dv),
                                  f2bf(a[2] * dv), f2bf(a[3] * dv) };
                    *(ushort4*)&g[(size_t)row * D + jt * 16 + g4 * 4] = o;
                }
            }
        }
    }
}

// ---------- sparse aggregation ----------
// quarter-wave (16 lanes x u16x8 = 256B) per node; bf16 gather, fp32 accum.
// out[v] = dis[v]*(sum_{u in slots(v)} g[u] + g[v]) + bias  (+ReLU / bf16-out)

template <bool RELU, bool OUT_BF16>
__global__ __launch_bounds__(256) void k_agg(const unsigned short* __restrict__ gtab,
                                             const int* __restrict__ cnt,
                                             const int* __restrict__ col,
                                             const float* __restrict__ bias,
                                             void* __restrict__ out, int N) {
    int node = blockIdx.x * 16 + (threadIdx.x >> 4);
    if (node >= N) return;
    int l16 = threadIdx.x & 15;
    const u16x8* G = (const u16x8*)gtab;    // 16 u16x8 per row
    float acc[8];
    {
        u16x8 s = G[(size_t)node * 16 + l16];   // self-loop term g[v]
#pragma unroll
        for (int j = 0; j < 8; j++) acc[j] = bf2f(s[j]);
    }
    int deg = cnt[node];
    const int* cbase = col + (size_t)node * CAP;
    int i = 0;
    for (; i + 3 < deg; i += 4) {
        int u0 = cbase[i], u1 = cbase[i + 1], u2 = cbase[i + 2], u3 = cbase[i + 3];
        u16x8 m0 = G[(size_t)u0 * 16 + l16];
        u16x8 m1 = G[(size_t)u1 * 16 + l16];
        u16x8 m2 = G[(size_t)u2 * 16 + l16];
        u16x8 m3 = G[(size_t)u3 * 16 + l16];
#pragma unroll
        for (int j = 0; j < 8; j++)
            acc[j] += (bf2f(m0[j]) + bf2f(m1[j])) + (bf2f(m2[j]) + bf2f(m3[j]));
    }
    for (; i < deg; i++) {
        u16x8 m = G[(size_t)cbase[i] * 16 + l16];
#pragma unroll
        for (int j = 0; j < 8; j++) acc[j] += bf2f(m[j]);
    }
    float s = rsqrtf((float)(deg + 1));     // dis[node]
    const float4* B4 = (const float4*)bias;
    float4 bb0 = B4[l16 * 2], bb1 = B4[l16 * 2 + 1];
    float r[8];
    r[0] = fmaf(acc[0], s, bb0.x); r[1] = fmaf(acc[1], s, bb0.y);
    r[2] = fmaf(acc[2], s, bb0.z); r[3] = fmaf(acc[3], s, bb0.w);
    r[4] = fmaf(acc[4], s, bb1.x); r[5] = fmaf(acc[5], s, bb1.y);
    r[6] = fmaf(acc[6], s, bb1.z); r[7] = fmaf(acc[7], s, bb1.w);
    if (RELU) {
#pragma unroll
        for (int j = 0; j < 8; j++) r[j] = fmaxf(r[j], 0.f);
    }
    if (OUT_BF16) {
        u16x8 o;
#pragma unroll
        for (int j = 0; j < 8; j++) o[j] = f2bf(r[j]);
        ((u16x8*)out)[(size_t)node * 16 + l16] = o;
    } else {
        float4 o0 = make_float4(r[0], r[1], r[2], r[3]);
        float4 o1 = make_float4(r[4], r[5], r[6], r[7]);
        ((float4*)out)[(size_t)node * 32 + l16 * 2]     = o0;
        ((float4*)out)[(size_t)node * 32 + l16 * 2 + 1] = o1;
    }
}

// ---------- launch ----------

extern "C" void kernel_launch(void* const* d_in, const int* in_sizes, int n_in,
                              void* d_out, int out_size, void* d_ws, size_t ws_size,
                              hipStream_t stream) {
    const float* x  = (const float*)d_in[0];
    const int*   ei = (const int*)d_in[1];
    const float* W1 = (const float*)d_in[2];
    const float* b1 = (const float*)d_in[3];
    const float* W2 = (const float*)d_in[4];
    const float* b2 = (const float*)d_in[5];
    float* out = (float*)d_out;

    int N = in_sizes[0] / D;
    int E = in_sizes[1] / 2;

    int NB  = (N + 63) >> 6;     // buckets (64 nodes each)
    int NSH = NB * 8;            // shards

    // ws: g (bf16 N*D, 25.6MB) | cnt (0.4MB) | col (N*CAP*4, 19.2MB)
    //   | bcnt (NSH*4, 50KB) | brec (NSH*SCAP*4, 8MB)   -> ~53.3 MB
    char* w = (char*)d_ws;
    unsigned short* g = (unsigned short*)w;  size_t off = (size_t)N * D * 2;
    off = (off + 255) & ~(size_t)255;
    int* cnt  = (int*)(w + off);             off += (size_t)N * 4;
    off = (off + 255) & ~(size_t)255;
    int* col  = (int*)(w + off);             off += (size_t)N * CAP * 4;
    off = (off + 255) & ~(size_t)255;
    int* bcnt = (int*)(w + off);             off += (size_t)NSH * 4;
    off = (off + 255) & ~(size_t)255;
    unsigned* brec = (unsigned*)(w + off);   off += (size_t)NSH * SCAP * 4;
    // intermediate h (bf16 N*D = 25.6 MB) lives in d_out (free until final agg)
    unsigned short* h = (unsigned short*)d_out;

    int ntiles = (N + 127) / 128;
    int gemm_grid = ntiles < 512 ? ntiles : 512;

    hipMemsetAsync(bcnt, 0, (size_t)NSH * 4, stream);
    k_bucket<<<(E / 4 + 255) / 256, 256, 0, stream>>>(ei, bcnt, brec, E);
    k_build<<<NB, 256, 0, stream>>>(bcnt, brec, cnt, col, N);

    // layer 1: g = bf16((x @ W1^T)*dis) ; h = bf16(relu(agg + b1)) -> d_out
    k_gemm_mfma<false><<<gemm_grid, 256, 0, stream>>>(x, W1, cnt, g, N, ntiles);
    k_agg<true, true><<<(N + 15) / 16, 256, 0, stream>>>(g, cnt, col, b1, h, N);

    // layer 2: g = bf16((h @ W2^T)*dis) ; out = agg + b2 (fp32) -> d_out
    k_gemm_mfma<true><<<gemm_grid, 256, 0, stream>>>(h, W2, cnt, g, N, ntiles);
    k_agg<false, false><<<(N + 15) / 16, 256, 0, stream>>>(g, cnt, col, b2, out, N);
}

// Round 9
// 167.179 us; speedup vs baseline: 1.1135x; 1.1135x over previous
//
#include <hip/hip_runtime.h>

#define D 128
#define CAP 48      // col slots per node; P(Poisson(8) >= 48) ~ 1e-35 * N -> safe

typedef __attribute__((ext_vector_type(8))) short bf16x8;
typedef __attribute__((ext_vector_type(4))) float f32x4;
typedef __attribute__((ext_vector_type(8))) unsigned short u16x8;

// ---------- bf16 helpers (manual, RNE) ----------
__device__ inline unsigned short f2bf(float f) {
    unsigned u = __float_as_uint(f);
    return (unsigned short)((u + 0x7fff + ((u >> 16) & 1)) >> 16);
}
__device__ inline float bf2f(unsigned short s) {
    return __uint_as_float((unsigned)s << 16);
}
__device__ inline bf16x8 cvt8(const float* __restrict__ p) {
    float4 a = *(const float4*)p;
    float4 b = *(const float4*)(p + 4);
    bf16x8 r;
    r[0] = (short)f2bf(a.x); r[1] = (short)f2bf(a.y);
    r[2] = (short)f2bf(a.z); r[3] = (short)f2bf(a.w);
    r[4] = (short)f2bf(b.x); r[5] = (short)f2bf(b.y);
    r[6] = (short)f2bf(b.z); r[7] = (short)f2bf(b.w);
    return r;
}

// ---------- prep: W1,W2 fp32 -> bf16 tables; zero degree counters ----------
__global__ void k_prep(const float* __restrict__ W1, const float* __restrict__ W2,
                       unsigned short* __restrict__ Wb1, unsigned short* __restrict__ Wb2,
                       int* __restrict__ cnt, int N) {
    int i = blockIdx.x * 256 + threadIdx.x;
    if (i < D * D) { Wb1[i] = f2bf(W1[i]); Wb2[i] = f2bf(W2[i]); }
    if (i < N) cnt[i] = 0;
}

// ---------- zero-LDS MFMA gemm tile (128 nodes per block, 32 per wave) -----
// C = W · x^T with mfma_f32_16x16x32_bf16. Fragments loaded straight from
// global: A-frag = Wb[jt*16+r16][g4*8+ks*32..] (bf16, 64KB L2-hot);
// B-frag = in[row][g4*8+ks*32..]. Per (r16,ks) the 4 g4-lanes cover a
// contiguous 64B(bf16)/128B(fp32) row segment -> full line utilization.
// C layout (m89-verified): col(lane&15)=node, row=(lane>>4)*4+reg.
// No LDS, no barriers -> co-schedules freely with the fill role.
// #pragma unroll 1 on ks-loop: round-3 lesson (full unroll -> hoist/spill).

template <bool INBF16, bool FOLD>
__device__ inline void gemm_tile(const void* __restrict__ in_v,
                                 const unsigned short* __restrict__ Wb,
                                 const int* __restrict__ cnt,
                                 unsigned short* __restrict__ g,
                                 int N, int tile, int t) {
    int w = t >> 6, l = t & 63;
    int r16 = l & 15, g4 = l >> 4;
    int base = tile * 128 + w * 32;
    int row0 = base + r16, row1 = row0 + 16;
    int cr0 = (row0 < N) ? row0 : N - 1;       // clamp loads on tail tile
    int cr1 = (row1 < N) ? row1 : N - 1;

    f32x4 acc0[8] = {};
    f32x4 acc1[8] = {};
    const unsigned short* wr = Wb + r16 * D + g4 * 8;

#pragma unroll 1
    for (int ks = 0; ks < 4; ks++) {
        bf16x8 b0, b1;
        if (INBF16) {
            const unsigned short* h = (const unsigned short*)in_v;
            b0 = *(const bf16x8*)(h + (size_t)cr0 * D + g4 * 8 + ks * 32);
            b1 = *(const bf16x8*)(h + (size_t)cr1 * D + g4 * 8 + ks * 32);
        } else {
            const float* xx = (const float*)in_v;
            b0 = cvt8(xx + (size_t)cr0 * D + g4 * 8 + ks * 32);
            b1 = cvt8(xx + (size_t)cr1 * D + g4 * 8 + ks * 32);
        }
#pragma unroll
        for (int jt = 0; jt < 8; jt++) {
            bf16x8 a = *(const bf16x8*)(wr + jt * 16 * D + ks * 32);
            acc0[jt] = __builtin_amdgcn_mfma_f32_16x16x32_bf16(a, b0, acc0[jt], 0, 0, 0);
            acc1[jt] = __builtin_amdgcn_mfma_f32_16x16x32_bf16(a, b1, acc1[jt], 0, 0, 0);
        }
    }

#pragma unroll
    for (int tt = 0; tt < 2; tt++) {
        int row = base + tt * 16 + r16;
        if (row < N) {
            float dv = 1.0f;
            if (FOLD) {
                int dg = cnt[row]; if (dg > CAP) dg = CAP;
                dv = rsqrtf((float)(dg + 1));
            }
#pragma unroll
            for (int jt = 0; jt < 8; jt++) {
                f32x4 a = tt ? acc1[jt] : acc0[jt];
                ushort4 o = { f2bf(a[0] * dv), f2bf(a[1] * dv),
                              f2bf(a[2] * dv), f2bf(a[3] * dv) };
                *(ushort4*)&g[(size_t)row * D + jt * 16 + g4 * 4] = o;
            }
        }
    }
}

// ---------- fused K1: graph fill (1/3 of blocks)  ||  gemm1 (2/3) ----------
// Roles are independent (fill: ei->cursor,col ; gemm: x,Wb1->g); agg1 (next
// kernel) is the join. Fill is a structural random-line wall (~50us constant
// across occupancy 26-54%, rounds 6-8) -> hide it under the GEMM.
// NOTE: harness delivers integer inputs as int32 (edge_index arrives as int*).

__global__ __launch_bounds__(256) void k_fill_gemm1(
        const int* __restrict__ ei, int* __restrict__ cursor, int* __restrict__ col,
        const float* __restrict__ x, const unsigned short* __restrict__ Wb1,
        unsigned short* __restrict__ g, int N, int E, int ntiles, int fillB) {
    int bid = blockIdx.x;
    if (bid % 3 == 2) {                         // ---- fill role ----
        int tid = (bid / 3) * 256 + threadIdx.x;
        int nthr = fillB * 256;
        int nq = (E + 3) >> 2;
        bool vec4 = (E & 3) == 0;
        for (int q = tid; q < nq; q += nthr) {
            int e0 = q * 4;
            if (vec4 && e0 + 3 < E) {
                int4 s4 = *(const int4*)&ei[e0];
                int4 d4 = *(const int4*)&ei[E + e0];
                int p0 = atomicAdd(&cursor[d4.x], 1);
                int p1 = atomicAdd(&cursor[d4.y], 1);
                int p2 = atomicAdd(&cursor[d4.z], 1);
                int p3 = atomicAdd(&cursor[d4.w], 1);
                if (p0 < CAP) col[d4.x * CAP + p0] = s4.x;
                if (p1 < CAP) col[d4.y * CAP + p1] = s4.y;
                if (p2 < CAP) col[d4.z * CAP + p2] = s4.z;
                if (p3 < CAP) col[d4.w * CAP + p3] = s4.w;
            } else {
                int eend = (e0 + 4 < E) ? e0 + 4 : E;
                for (int e = e0; e < eend; e++) {
                    int s = ei[e], d = ei[E + e];
                    int p = atomicAdd(&cursor[d], 1);
                    if (p < CAP) col[d * CAP + p] = s;
                }
            }
        }
    } else {                                    // ---- gemm1 role ----
        int gid = (bid / 3) * 2 + (bid % 3);
        if (gid >= ntiles) return;
        gemm_tile<false, false>(x, Wb1, nullptr, g, N, gid, threadIdx.x);
    }
}

// ---------- standalone gemm2 (dis-folded) ----------
__global__ __launch_bounds__(256) void k_gemm2(
        const unsigned short* __restrict__ h, const unsigned short* __restrict__ Wb2,
        const int* __restrict__ cnt, unsigned short* __restrict__ g, int N, int ntiles) {
    if ((int)blockIdx.x >= ntiles) return;
    gemm_tile<true, true>(h, Wb2, cnt, g, N, blockIdx.x, threadIdx.x);
}

// ---------- sparse aggregation ----------
// quarter-wave (16 lanes x u16x8 = 256B) per node; bf16 gather, fp32 accum.
// DISU (layer 1): g is unnormalized -> per-edge multiply by rsqrt(deg[u]+1)
// (cnt[u] is a broadcast line; dis fold couldn't live in gemm1 since cnt is
// written concurrently by the fused fill role).

template <bool RELU, bool OUT_BF16, bool DISU>
__global__ __launch_bounds__(256) void k_agg(const unsigned short* __restrict__ gtab,
                                             const int* __restrict__ cnt,
                                             const int* __restrict__ col,
                                             const float* __restrict__ bias,
                                             void* __restrict__ out, int N) {
    int node = blockIdx.x * 16 + (threadIdx.x >> 4);
    if (node >= N) return;
    int l16 = threadIdx.x & 15;
    const u16x8* G = (const u16x8*)gtab;    // 16 u16x8 per row
    int deg = cnt[node]; if (deg > CAP) deg = CAP;
    float disv = rsqrtf((float)(deg + 1));
    float acc[8];
    {
        u16x8 s = G[(size_t)node * 16 + l16];   // self-loop term
        float sf = DISU ? disv : 1.0f;          // g[v]*dis_v if unnormalized
#pragma unroll
        for (int j = 0; j < 8; j++) acc[j] = bf2f(s[j]) * sf;
    }
    const int* cbase = col + (size_t)node * CAP;
    int i = 0;
    for (; i + 3 < deg; i += 4) {
        int u0 = cbase[i], u1 = cbase[i + 1], u2 = cbase[i + 2], u3 = cbase[i + 3];
        u16x8 m0 = G[(size_t)u0 * 16 + l16];
        u16x8 m1 = G[(size_t)u1 * 16 + l16];
        u16x8 m2 = G[(size_t)u2 * 16 + l16];
        u16x8 m3 = G[(size_t)u3 * 16 + l16];
        if (DISU) {
            int c0 = cnt[u0], c1 = cnt[u1], c2 = cnt[u2], c3 = cnt[u3];
            float d0 = rsqrtf((float)((c0 > CAP ? CAP : c0) + 1));
            float d1 = rsqrtf((float)((c1 > CAP ? CAP : c1) + 1));
            float d2 = rsqrtf((float)((c2 > CAP ? CAP : c2) + 1));
            float d3 = rsqrtf((float)((c3 > CAP ? CAP : c3) + 1));
#pragma unroll
            for (int j = 0; j < 8; j++)
                acc[j] += (bf2f(m0[j]) * d0 + bf2f(m1[j]) * d1)
                        + (bf2f(m2[j]) * d2 + bf2f(m3[j]) * d3);
        } else {
#pragma unroll
            for (int j = 0; j < 8; j++)
                acc[j] += (bf2f(m0[j]) + bf2f(m1[j])) + (bf2f(m2[j]) + bf2f(m3[j]));
        }
    }
    for (; i < deg; i++) {
        int u = cbase[i];
        u16x8 m = G[(size_t)u * 16 + l16];
        float du = 1.0f;
        if (DISU) { int c = cnt[u]; du = rsqrtf((float)((c > CAP ? CAP : c) + 1)); }
#pragma unroll
        for (int j = 0; j < 8; j++) acc[j] += bf2f(m[j]) * du;
    }
    const float4* B4 = (const float4*)bias;
    float4 bb0 = B4[l16 * 2], bb1 = B4[l16 * 2 + 1];
    float r[8];
    r[0] = fmaf(acc[0], disv, bb0.x); r[1] = fmaf(acc[1], disv, bb0.y);
    r[2] = fmaf(acc[2], disv, bb0.z); r[3] = fmaf(acc[3], disv, bb0.w);
    r[4] = fmaf(acc[4], disv, bb1.x); r[5] = fmaf(acc[5], disv, bb1.y);
    r[6] = fmaf(acc[6], disv, bb1.z); r[7] = fmaf(acc[7], disv, bb1.w);
    if (RELU) {
#pragma unroll
        for (int j = 0; j < 8; j++) r[j] = fmaxf(r[j], 0.f);
    }
    if (OUT_BF16) {
        u16x8 o;
#pragma unroll
        for (int j = 0; j < 8; j++) o[j] = f2bf(r[j]);
        ((u16x8*)out)[(size_t)node * 16 + l16] = o;
    } else {
        float4 o0 = make_float4(r[0], r[1], r[2], r[3]);
        float4 o1 = make_float4(r[4], r[5], r[6], r[7]);
        ((float4*)out)[(size_t)node * 32 + l16 * 2]     = o0;
        ((float4*)out)[(size_t)node * 32 + l16 * 2 + 1] = o1;
    }
}

// ---------- launch ----------

extern "C" void kernel_launch(void* const* d_in, const int* in_sizes, int n_in,
                              void* d_out, int out_size, void* d_ws, size_t ws_size,
                              hipStream_t stream) {
    const float* x  = (const float*)d_in[0];
    const int*   ei = (const int*)d_in[1];
    const float* W1 = (const float*)d_in[2];
    const float* b1 = (const float*)d_in[3];
    const float* W2 = (const float*)d_in[4];
    const float* b2 = (const float*)d_in[5];
    float* out = (float*)d_out;

    int N = in_sizes[0] / D;
    int E = in_sizes[1] / 2;

    // ws: g (bf16 N*D, 25.6MB) | cnt (0.4MB) | col (N*CAP*4, 19.2MB) | Wb1|Wb2
    char* w = (char*)d_ws;
    unsigned short* g = (unsigned short*)w;  size_t off = (size_t)N * D * 2;
    off = (off + 255) & ~(size_t)255;
    int* cnt  = (int*)(w + off);             off += (size_t)N * 4;
    off = (off + 255) & ~(size_t)255;
    int* col  = (int*)(w + off);             off += (size_t)N * CAP * 4;
    off = (off + 255) & ~(size_t)255;
    unsigned short* Wb1 = (unsigned short*)(w + off); off += (size_t)D * D * 2;
    unsigned short* Wb2 = (unsigned short*)(w + off); off += (size_t)D * D * 2;
    // intermediate h (bf16 N*D = 25.6 MB) lives in d_out (free until final agg)
    unsigned short* h = (unsigned short*)d_out;

    int ntiles = (N + 127) / 128;
    int fillB  = (ntiles + 1) / 2;           // 1 fill block per 2 gemm blocks
    int total  = ntiles + fillB;

    k_prep<<<(N + 255) / 256, 256, 0, stream>>>(W1, W2, Wb1, Wb2, cnt, N);

    // K1: fill (ei -> cursor,col)  ||  gemm1 (g = bf16(x @ W1^T), no dis)
    k_fill_gemm1<<<total, 256, 0, stream>>>(ei, cnt, col, x, Wb1, g, N, E, ntiles, fillB);

    // agg1: h = bf16(relu(dis_v*(sum g[u]*dis_u + g[v]*dis_v) + b1)) -> d_out
    k_agg<true, true, true><<<(N + 15) / 16, 256, 0, stream>>>(g, cnt, col, b1, h, N);

    // gemm2: g = bf16((h @ W2^T) * dis)
    k_gemm2<<<ntiles, 256, 0, stream>>>(h, Wb2, cnt, g, N, ntiles);

    // agg2: out = dis_v*(sum g[u] + g[v]) + b2  (fp32) -> d_out
    k_agg<false, false, false><<<(N + 15) / 16, 256, 0, stream>>>(g, cnt, col, b2, out, N);
}

// Round 10
// 160.085 us; speedup vs baseline: 1.1629x; 1.0443x over previous
//
#include <hip/hip_runtime.h>

#define D 128
#define CAP 48      // col slots per node; P(Poisson(8) >= 48) ~ 1e-35 * N -> safe
#define BE 4096     // edges per sort block
#define SC 5120     // brec records per bucket (Poisson(4096), 16-sigma headroom)

typedef __attribute__((ext_vector_type(8))) short bf16x8;
typedef __attribute__((ext_vector_type(4))) float f32x4;
typedef __attribute__((ext_vector_type(8))) unsigned short u16x8;

// ---------- bf16 helpers (manual, RNE) ----------
__device__ inline unsigned short f2bf(float f) {
    unsigned u = __float_as_uint(f);
    return (unsigned short)((u + 0x7fff + ((u >> 16) & 1)) >> 16);
}
__device__ inline float bf2f(unsigned short s) {
    return __uint_as_float((unsigned)s << 16);
}
__device__ inline bf16x8 cvt8(const float* __restrict__ p) {
    float4 a = *(const float4*)p;
    float4 b = *(const float4*)(p + 4);
    bf16x8 r;
    r[0] = (short)f2bf(a.x); r[1] = (short)f2bf(a.y);
    r[2] = (short)f2bf(a.z); r[3] = (short)f2bf(a.w);
    r[4] = (short)f2bf(b.x); r[5] = (short)f2bf(b.y);
    r[6] = (short)f2bf(b.z); r[7] = (short)f2bf(b.w);
    return r;
}

// ---------- prep: W1,W2 fp32 -> bf16 tables; zero bucket counters ----------
__global__ void k_prep(const float* __restrict__ W1, const float* __restrict__ W2,
                       unsigned short* __restrict__ Wb1, unsigned short* __restrict__ Wb2,
                       int* __restrict__ bcnt, int NBK) {
    int i = blockIdx.x * 256 + threadIdx.x;
    if (i < D * D) { Wb1[i] = f2bf(W1[i]); Wb2[i] = f2bf(W2[i]); }
    if (i < NBK) bcnt[i] = 0;
}

// ---------- zero-LDS MFMA gemm tile (128 nodes per block, 32 per wave) -----
// C = W · x^T with mfma_f32_16x16x32_bf16; fragments straight from global
// (Wb 64KB stays L2-hot). C layout (m89): col(lane&15)=node, row=(lane>>4)*4+reg.
// No LDS/barriers -> co-schedules freely with the sort role.
// #pragma unroll 1 on ks-loop: round-3 lesson (full unroll -> hoist/spill).

template <bool INBF16, bool FOLD>
__device__ inline void gemm_tile(const void* __restrict__ in_v,
                                 const unsigned short* __restrict__ Wb,
                                 const int* __restrict__ cnt,
                                 unsigned short* __restrict__ g,
                                 int N, int tile, int t) {
    int w = t >> 6, l = t & 63;
    int r16 = l & 15, g4 = l >> 4;
    int base = tile * 128 + w * 32;
    int row0 = base + r16, row1 = row0 + 16;
    int cr0 = (row0 < N) ? row0 : N - 1;       // clamp loads on tail tile
    int cr1 = (row1 < N) ? row1 : N - 1;

    f32x4 acc0[8] = {};
    f32x4 acc1[8] = {};
    const unsigned short* wr = Wb + r16 * D + g4 * 8;

#pragma unroll 1
    for (int ks = 0; ks < 4; ks++) {
        bf16x8 b0, b1;
        if (INBF16) {
            const unsigned short* h = (const unsigned short*)in_v;
            b0 = *(const bf16x8*)(h + (size_t)cr0 * D + g4 * 8 + ks * 32);
            b1 = *(const bf16x8*)(h + (size_t)cr1 * D + g4 * 8 + ks * 32);
        } else {
            const float* xx = (const float*)in_v;
            b0 = cvt8(xx + (size_t)cr0 * D + g4 * 8 + ks * 32);
            b1 = cvt8(xx + (size_t)cr1 * D + g4 * 8 + ks * 32);
        }
#pragma unroll
        for (int jt = 0; jt < 8; jt++) {
            bf16x8 a = *(const bf16x8*)(wr + jt * 16 * D + ks * 32);
            acc0[jt] = __builtin_amdgcn_mfma_f32_16x16x32_bf16(a, b0, acc0[jt], 0, 0, 0);
            acc1[jt] = __builtin_amdgcn_mfma_f32_16x16x32_bf16(a, b1, acc1[jt], 0, 0, 0);
        }
    }

#pragma unroll
    for (int tt = 0; tt < 2; tt++) {
        int row = base + tt * 16 + r16;
        if (row < N) {
            float dv = 1.0f;
            if (FOLD) {
                int dg = cnt[row]; if (dg > CAP) dg = CAP;
                dv = rsqrtf((float)(dg + 1));
            }
#pragma unroll
            for (int jt = 0; jt < 8; jt++) {
                f32x4 a = tt ? acc1[jt] : acc0[jt];
                ushort4 o = { f2bf(a[0] * dv), f2bf(a[1] * dv),
                              f2bf(a[2] * dv), f2bf(a[3] * dv) };
                *(ushort4*)&g[(size_t)row * D + jt * 16 + g4 * 4] = o;
            }
        }
    }
}

// ---------- fused K1: edge counting-sort (1/5 of blocks) || gemm1 (4/5) ----
// Sort role: per block, 4096 edges -> LDS counting sort by bucket dst>>9
// (196 buckets), reserve global ranges with 196 atomics, stream records out
// in bucket order (consecutive lanes -> consecutive addrs, coalesced).
// Replaces the random 4B line-RMW scatter (rounds 6-9: constant ~50us wall,
// 47MB line traffic for 3.2MB payload). Record = (src<<9)|(dst&511), fits
// u32 since N < 2^17. No XCD assumptions (round-8 lesson).
// NOTE: harness delivers integer inputs as int32 (edge_index arrives as int*).

__global__ __launch_bounds__(256) void k_sort_gemm1(
        const int* __restrict__ ei, int* __restrict__ bcnt, unsigned* __restrict__ brec,
        const float* __restrict__ x, const unsigned short* __restrict__ Wb1,
        unsigned short* __restrict__ g, int N, int E, int ntiles, int fb, int NBK) {
    int bid = blockIdx.x;
    if (bid % 5 == 4) {                         // ---- sort role ----
        __shared__ unsigned srt[BE];            // 16 KB sorted records
        __shared__ unsigned char bko[BE];       // 4 KB bucket of position
        __shared__ int hist[256];
        __shared__ int pfx[256];
        __shared__ int gbase[256];
        __shared__ int cur[256];
        int f = bid / 5;
        if (f >= fb) return;
        int t = threadIdx.x;
        int e0 = f * BE;
        int n = E - e0; if (n > BE) n = BE;

        hist[t] = 0; cur[t] = 0;
        __syncthreads();

        unsigned rec[16]; int mb[16];
#pragma unroll
        for (int j = 0; j < 16; j++) {
            int e = e0 + j * 256 + t;           // coalesced
            if (e < E) {
                int s = ei[e], d = ei[E + e];
                rec[j] = ((unsigned)s << 9) | (unsigned)(d & 511);
                mb[j] = d >> 9;
                atomicAdd(&hist[mb[j]], 1);
            } else mb[j] = -1;
        }
        __syncthreads();
        int v = hist[t];                        // inclusive scan -> exclusive
        pfx[t] = v;
        __syncthreads();
        for (int dd = 1; dd < 256; dd <<= 1) {
            int xv = (t >= dd) ? pfx[t - dd] : 0;
            __syncthreads();
            pfx[t] += xv;
            __syncthreads();
        }
        pfx[t] -= v;                            // exclusive prefix
        if (v > 0 && t < NBK) gbase[t] = atomicAdd(&bcnt[t], v);
        __syncthreads();
#pragma unroll
        for (int j = 0; j < 16; j++) {
            if (mb[j] >= 0) {
                int p = pfx[mb[j]] + atomicAdd(&cur[mb[j]], 1);
                srt[p] = rec[j];
                bko[p] = (unsigned char)mb[j];
            }
        }
        __syncthreads();
        for (int i = t; i < n; i += 256) {      // bucket-ordered -> coalesced runs
            int b = bko[i];
            int pos = gbase[b] + (i - pfx[b]);
            if (pos < SC) brec[(size_t)b * SC + pos] = srt[i];
        }
    } else {                                    // ---- gemm1 role ----
        int gid = (bid / 5) * 4 + (bid % 5);
        if (gid >= ntiles) return;
        gemm_tile<false, false>(x, Wb1, nullptr, g, N, gid, threadIdx.x);
    }
}

// ---------- build: one block per bucket -> col slot-table + degrees --------
// Bucket's col window = 512*CAP*4 = 98KB, temporally clustered -> L2-merged.

__global__ __launch_bounds__(256) void k_build(const int* __restrict__ bcnt,
                                               const unsigned* __restrict__ brec,
                                               int* __restrict__ cnt,
                                               int* __restrict__ col, int N) {
    __shared__ int c512[512];
    int b = blockIdx.x, t = threadIdx.x;
    c512[t] = 0; c512[t + 256] = 0;
    __syncthreads();
    int total = bcnt[b]; if (total > SC) total = SC;
    for (int i = t; i < total; i += 256) {
        unsigned rec = brec[(size_t)b * SC + i];
        int dl = rec & 511;
        int p = atomicAdd(&c512[dl], 1);
        if (p < CAP) col[(size_t)(b * 512 + dl) * CAP + p] = (int)(rec >> 9);
    }
    __syncthreads();
#pragma unroll
    for (int k = 0; k < 2; k++) {
        int dl = t + k * 256;
        int node = b * 512 + dl;
        if (node < N) cnt[node] = (c512[dl] < CAP) ? c512[dl] : CAP;
    }
}

// ---------- standalone gemm2 (dis-folded) ----------
__global__ __launch_bounds__(256) void k_gemm2(
        const unsigned short* __restrict__ h, const unsigned short* __restrict__ Wb2,
        const int* __restrict__ cnt, unsigned short* __restrict__ g, int N, int ntiles) {
    if ((int)blockIdx.x >= ntiles) return;
    gemm_tile<true, true>(h, Wb2, cnt, g, N, blockIdx.x, threadIdx.x);
}

// ---------- sparse aggregation ----------
// quarter-wave (16 lanes x u16x8 = 256B) per node; bf16 gather, fp32 accum.
// DISU (layer 1): g unnormalized -> per-edge rsqrt(deg[u]+1) (cnt not ready
// during the fused gemm1).

template <bool RELU, bool OUT_BF16, bool DISU>
__global__ __launch_bounds__(256) void k_agg(const unsigned short* __restrict__ gtab,
                                             const int* __restrict__ cnt,
                                             const int* __restrict__ col,
                                             const float* __restrict__ bias,
                                             void* __restrict__ out, int N) {
    int node = blockIdx.x * 16 + (threadIdx.x >> 4);
    if (node >= N) return;
    int l16 = threadIdx.x & 15;
    const u16x8* G = (const u16x8*)gtab;    // 16 u16x8 per row
    int deg = cnt[node];
    float disv = rsqrtf((float)(deg + 1));
    float acc[8];
    {
        u16x8 s = G[(size_t)node * 16 + l16];   // self-loop term
        float sf = DISU ? disv : 1.0f;
#pragma unroll
        for (int j = 0; j < 8; j++) acc[j] = bf2f(s[j]) * sf;
    }
    const int* cbase = col + (size_t)node * CAP;
    int i = 0;
    for (; i + 3 < deg; i += 4) {
        int u0 = cbase[i], u1 = cbase[i + 1], u2 = cbase[i + 2], u3 = cbase[i + 3];
        u16x8 m0 = G[(size_t)u0 * 16 + l16];
        u16x8 m1 = G[(size_t)u1 * 16 + l16];
        u16x8 m2 = G[(size_t)u2 * 16 + l16];
        u16x8 m3 = G[(size_t)u3 * 16 + l16];
        if (DISU) {
            float d0 = rsqrtf((float)(cnt[u0] + 1));
            float d1 = rsqrtf((float)(cnt[u1] + 1));
            float d2 = rsqrtf((float)(cnt[u2] + 1));
            float d3 = rsqrtf((float)(cnt[u3] + 1));
#pragma unroll
            for (int j = 0; j < 8; j++)
                acc[j] += (bf2f(m0[j]) * d0 + bf2f(m1[j]) * d1)
                        + (bf2f(m2[j]) * d2 + bf2f(m3[j]) * d3);
        } else {
#pragma unroll
            for (int j = 0; j < 8; j++)
                acc[j] += (bf2f(m0[j]) + bf2f(m1[j])) + (bf2f(m2[j]) + bf2f(m3[j]));
        }
    }
    for (; i < deg; i++) {
        int u = cbase[i];
        u16x8 m = G[(size_t)u * 16 + l16];
        float du = DISU ? rsqrtf((float)(cnt[u] + 1)) : 1.0f;
#pragma unroll
        for (int j = 0; j < 8; j++) acc[j] += bf2f(m[j]) * du;
    }
    const float4* B4 = (const float4*)bias;
    float4 bb0 = B4[l16 * 2], bb1 = B4[l16 * 2 + 1];
    float r[8];
    r[0] = fmaf(acc[0], disv, bb0.x); r[1] = fmaf(acc[1], disv, bb0.y);
    r[2] = fmaf(acc[2], disv, bb0.z); r[3] = fmaf(acc[3], disv, bb0.w);
    r[4] = fmaf(acc[4], disv, bb1.x); r[5] = fmaf(acc[5], disv, bb1.y);
    r[6] = fmaf(acc[6], disv, bb1.z); r[7] = fmaf(acc[7], disv, bb1.w);
    if (RELU) {
#pragma unroll
        for (int j = 0; j < 8; j++) r[j] = fmaxf(r[j], 0.f);
    }
    if (OUT_BF16) {
        u16x8 o;
#pragma unroll
        for (int j = 0; j < 8; j++) o[j] = f2bf(r[j]);
        ((u16x8*)out)[(size_t)node * 16 + l16] = o;
    } else {
        float4 o0 = make_float4(r[0], r[1], r[2], r[3]);
        float4 o1 = make_float4(r[4], r[5], r[6], r[7]);
        ((float4*)out)[(size_t)node * 32 + l16 * 2]     = o0;
        ((float4*)out)[(size_t)node * 32 + l16 * 2 + 1] = o1;
    }
}

// ---------- launch ----------

extern "C" void kernel_launch(void* const* d_in, const int* in_sizes, int n_in,
                              void* d_out, int out_size, void* d_ws, size_t ws_size,
                              hipStream_t stream) {
    const float* x  = (const float*)d_in[0];
    const int*   ei = (const int*)d_in[1];
    const float* W1 = (const float*)d_in[2];
    const float* b1 = (const float*)d_in[3];
    const float* W2 = (const float*)d_in[4];
    const float* b2 = (const float*)d_in[5];
    float* out = (float*)d_out;

    int N = in_sizes[0] / D;
    int E = in_sizes[1] / 2;
    int NBK = (N + 511) >> 9;                // 196 buckets of 512 nodes

    // ws: g 25.6MB | cnt 0.4MB | col (NBK*512*CAP*4) 19.3MB | Wb 64KB
    //   | bcnt 1KB | brec NBK*SC*4 = 4MB   -> ~49.4 MB
    char* w = (char*)d_ws;
    unsigned short* g = (unsigned short*)w;  size_t off = (size_t)N * D * 2;
    off = (off + 255) & ~(size_t)255;
    int* cnt  = (int*)(w + off);             off += (size_t)N * 4;
    off = (off + 255) & ~(size_t)255;
    int* col  = (int*)(w + off);             off += (size_t)NBK * 512 * CAP * 4;
    off = (off + 255) & ~(size_t)255;
    unsigned short* Wb1 = (unsigned short*)(w + off); off += (size_t)D * D * 2;
    unsigned short* Wb2 = (unsigned short*)(w + off); off += (size_t)D * D * 2;
    off = (off + 255) & ~(size_t)255;
    int* bcnt = (int*)(w + off);             off += (size_t)NBK * 4;
    off = (off + 255) & ~(size_t)255;
    unsigned* brec = (unsigned*)(w + off);   off += (size_t)NBK * SC * 4;
    // intermediate h (bf16 N*D = 25.6 MB) lives in d_out (free until final agg)
    unsigned short* h = (unsigned short*)d_out;

    int ntiles = (N + 127) / 128;
    int fillB  = (E + BE - 1) / BE;          // sort blocks
    int fb = fillB > (ntiles + 3) / 4 ? fillB : (ntiles + 3) / 4;
    int total  = 5 * fb;                     // 1 sort : 4 gemm interleave

    k_prep<<<(D * D + 255) / 256, 256, 0, stream>>>(W1, W2, Wb1, Wb2, bcnt, NBK);

    // K1: counting-sort (ei -> bcnt,brec)  ||  gemm1 (g = bf16(x @ W1^T))
    k_sort_gemm1<<<total, 256, 0, stream>>>(ei, bcnt, brec, x, Wb1, g, N, E,
                                            ntiles, fillB, NBK);
    // build: brec -> col slot-table + cnt (degrees)
    k_build<<<NBK, 256, 0, stream>>>(bcnt, brec, cnt, col, N);

    // agg1: h = bf16(relu(dis_v*(sum g[u]*dis_u + g[v]*dis_v) + b1)) -> d_out
    k_agg<true, true, true><<<(N + 15) / 16, 256, 0, stream>>>(g, cnt, col, b1, h, N);

    // gemm2: g = bf16((h @ W2^T) * dis)
    k_gemm2<<<ntiles, 256, 0, stream>>>(h, Wb2, cnt, g, N, ntiles);

    // agg2: out = dis_v*(sum g[u] + g[v]) + b2  (fp32) -> d_out
    k_agg<false, false, false><<<(N + 15) / 16, 256, 0, stream>>>(g, cnt, col, b2, out, N);
}